// Round 8
// baseline (660.902 us; speedup 1.0000x reference)
//
#include <hip/hip_runtime.h>
#include <cstdint>
#include <cstddef>

typedef unsigned short ushort_t;
typedef short    bf16x8 __attribute__((ext_vector_type(8)));   // MFMA A/B frag (4 VGPR)
typedef float    f32x4  __attribute__((ext_vector_type(4)));   // MFMA C/D frag
typedef uint4    __attribute__((may_alias)) uint4_a;
typedef ushort4  __attribute__((may_alias)) ushort4_a;
typedef float4   __attribute__((may_alias)) float4_a;
typedef unsigned __attribute__((may_alias)) uint_a;

constexpr int SEQ = 4096, HID = 2048, NHEADS = 16, NKVH = 4, HDIM = 128;
constexpr int QD  = NHEADS * HDIM;   // 2048
constexpr int KVD = NKVH * HDIM;     // 512
constexpr int KVL = 2 * KVD;         // 1024: interleaved k|v row stride

static __device__ __forceinline__ float bf2f(ushort_t u) {
    return __uint_as_float(((unsigned)u) << 16);
}
static __device__ __forceinline__ ushort_t f2bf(float f) {
    unsigned x = __float_as_uint(f);
    unsigned r = x + 0x7FFFu + ((x >> 16) & 1u);   // RNE
    return (ushort_t)(r >> 16);
}
static __device__ __forceinline__ unsigned pack2(float lo, float hi) {
    return (unsigned)f2bf(lo) | ((unsigned)f2bf(hi) << 16);
}

// async global->LDS, 16B per lane
static __device__ __forceinline__ void gld16(const ushort_t* g, ushort_t* l) {
    __builtin_amdgcn_global_load_lds(
        (const __attribute__((address_space(1))) unsigned*)g,
        (__attribute__((address_space(3))) unsigned*)l, 16, 0, 0);
}

// ---------------------------------------------------------------------------
// X fp32 -> bf16 elementwise
// ---------------------------------------------------------------------------
__global__ __launch_bounds__(256) void cast_f32_bf16(
    const float* __restrict__ in, ushort_t* __restrict__ out, int n)
{
    int i = (blockIdx.x * 256 + threadIdx.x) * 8;
    if (i >= n) return;
    float4 a = *(const float4_a*)(in + i);
    float4 b = *(const float4_a*)(in + i + 4);
    uint4 o;
    o.x = pack2(a.x, a.y); o.y = pack2(a.z, a.w);
    o.z = pack2(b.x, b.y); o.w = pack2(b.z, b.w);
    *(uint4_a*)(out + i) = o;
}

// ---------------------------------------------------------------------------
// W[K,N] fp32 -> WT[N,K] bf16 (32x32 LDS-tiled transpose+cast)
// ---------------------------------------------------------------------------
__global__ __launch_bounds__(256) void transpose_cast(
    const float* __restrict__ W, ushort_t* __restrict__ WT, int K, int N)
{
    __shared__ float tl[32][36];
    const int k0 = blockIdx.x * 32, n0 = blockIdx.y * 32;
    const int t  = threadIdx.x;
    {
        int i = t >> 3, jb = (t & 7) * 4;
        *(float4_a*)&tl[i][jb] = *(const float4_a*)(W + (size_t)(k0 + i) * N + n0 + jb);
    }
    __syncthreads();
    {
        int n = t >> 3, kb = (t & 7) * 4;
        ushort4 o;
        o.x = f2bf(tl[kb + 0][n]); o.y = f2bf(tl[kb + 1][n]);
        o.z = f2bf(tl[kb + 2][n]); o.w = f2bf(tl[kb + 3][n]);
        *(ushort4_a*)(WT + (size_t)(n0 + n) * K + k0 + kb) = o;
    }
}

// ---------------------------------------------------------------------------
// m97-style MFMA GEMM (unchanged from R7): C = A[M,K] * Bt[N,K]^T.
// ---------------------------------------------------------------------------
__global__ __launch_bounds__(256) void gemm_mfma(
    const ushort_t* __restrict__ A, int lda,
    const ushort_t* __restrict__ Bt, int ldb,
    void* __restrict__ C1, int ld1, void* __restrict__ C2, int ld2,
    int split, int N, int K, int out_f32)
{
    __shared__ ushort_t as[128 * 32];
    __shared__ ushort_t bs[128 * 32];

    const int t    = threadIdx.x;
    const int mb   = blockIdx.y * 128, nb = blockIdx.x * 128;
    const int w    = t >> 6, lane = t & 63, quad = lane >> 4, l15 = lane & 15;
    const int wm   = (w >> 1) * 64, wn = (w & 1) * 64;

    const int dr_row = lane >> 2, dr_c = lane & 3;
    const int rA0 = w * 16 + dr_row, rA1 = 64 + w * 16 + dr_row;
    const ushort_t* a0p = A  + (size_t)(mb + rA0) * lda + (dr_c ^ (rA0 & 3)) * 8;
    const ushort_t* a1p = A  + (size_t)(mb + rA1) * lda + (dr_c ^ (rA1 & 3)) * 8;
    const ushort_t* b0p = Bt + (size_t)(nb + rA0) * ldb + (dr_c ^ (rA0 & 3)) * 8;
    const ushort_t* b1p = Bt + (size_t)(nb + rA1) * ldb + (dr_c ^ (rA1 & 3)) * 8;
    ushort_t* asb0 = &as[(w) * 512];        ushort_t* asb1 = &as[(4 + w) * 512];
    ushort_t* bsb0 = &bs[(w) * 512];        ushort_t* bsb1 = &bs[(4 + w) * 512];

    f32x4 acc[4][4];
#pragma unroll
    for (int i = 0; i < 4; i++)
#pragma unroll
        for (int j = 0; j < 4; j++) acc[i][j] = (f32x4)0.f;

    const int chunk = quad ^ (l15 & 3);

    for (int kb = 0; kb < K; kb += 32) {
        __syncthreads();
        gld16(a0p + kb, asb0);
        gld16(a1p + kb, asb1);
        gld16(b0p + kb, bsb0);
        gld16(b1p + kb, bsb1);
        __syncthreads();

        bf16x8 af[4], bf[4];
#pragma unroll
        for (int mt = 0; mt < 4; mt++)
            af[mt] = *(const bf16x8*)&as[(wm + mt * 16 + l15) * 32 + chunk * 8];
#pragma unroll
        for (int nt = 0; nt < 4; nt++)
            bf[nt] = *(const bf16x8*)&bs[(wn + nt * 16 + l15) * 32 + chunk * 8];
#pragma unroll
        for (int mt = 0; mt < 4; mt++)
#pragma unroll
            for (int nt = 0; nt < 4; nt++)
                acc[mt][nt] = __builtin_amdgcn_mfma_f32_16x16x32_bf16(
                    af[mt], bf[nt], acc[mt][nt], 0, 0, 0);
    }

#pragma unroll
    for (int mt = 0; mt < 4; mt++)
#pragma unroll
        for (int nt = 0; nt < 4; nt++) {
            int colg = nb + wn + nt * 16 + l15;
#pragma unroll
            for (int r = 0; r < 4; r++) {
                int row = mb + wm + mt * 16 + quad * 4 + r;
                float v = acc[mt][nt][r];
                if (out_f32)            ((float*)C1)[(size_t)row * ld1 + colg] = v;
                else if (colg < split)  ((ushort_t*)C1)[(size_t)row * ld1 + colg] = f2bf(v);
                else                    ((ushort_t*)C2)[(size_t)row * ld2 + colg - split] = f2bf(v);
            }
        }
}

// ---------------------------------------------------------------------------
// RoPE in-place on bf16 [SEQ, ld] buffer, nh heads; precise sincosf.
// ---------------------------------------------------------------------------
__global__ __launch_bounds__(256) void rope_bf16(
    ushort_t* __restrict__ buf, int ld, int nh, const int* __restrict__ pos_ids)
{
    int idx  = blockIdx.x * 256 + threadIdx.x;
    int i    = idx & 63;
    int rem  = idx >> 6;
    int head = rem % nh;
    int s    = rem / nh;
    if (s >= SEQ) return;

    float pos = (float)pos_ids[s];
    float ang = pos * __expf(-(float)i * 0.14391156831212787f);
    float c, sn;
    sincosf(ang, &sn, &c);

    ushort_t* p = buf + (size_t)s * ld + head * HDIM;
    float x0 = bf2f(p[i]);
    float x1 = bf2f(p[i + 64]);
    p[i]      = f2bf(x0 * c - x1 * sn);
    p[i + 64] = f2bf(x1 * c + x0 * sn);
}

// ---------------------------------------------------------------------------
// Flash v4 (R8): 256 thr = 4 waves x 32 q-rows (128 q/block), 128-key staged
// tiles processed as two 64-key online-softmax sub-rounds. LDS unpadded +
// XOR-swizzled (chunk ^= row&7) -> conflict-free b128 frags. S^T = K*Q^T
// (key-reduction in regs + 2 shfl). P transposed in-register via ds_bpermute.
// K loads row-contiguous; V loads 2-key packs for the LDS transpose.
// Q/O alias in-place. 64.5 KB LDS -> 2 blocks/CU.
// ---------------------------------------------------------------------------
__global__ __launch_bounds__(256, 2) void flash_mfma(
    const ushort_t* Q, const ushort_t* __restrict__ KV,
    const int* __restrict__ amask, ushort_t* O)
{
    __shared__ ushort_t ks[128 * 128];   // [key][dim], swizzled
    __shared__ ushort_t vt[128 * 128];   // [dim][key], swizzled
    __shared__ float    bias[128];

    const int t = threadIdx.x, w = t >> 6, lane = t & 63;
    const int quad = lane >> 4, l15 = lane & 15;
    const int h = blockIdx.x, kvh = h >> 2;
    const int q0 = (gridDim.y - 1 - blockIdx.y) * 128;   // big tiles first
    const int q0w = q0 + w * 32;
    const int kcol = kvh * HDIM, vcol = KVD + kvh * HDIM;

    // Q B-frags, 2 q-subtiles of 16
    bf16x8 qf[2][4];
#pragma unroll
    for (int nt = 0; nt < 2; nt++) {
        const ushort_t* qp = Q + (size_t)(q0w + nt * 16 + l15) * QD + h * HDIM;
#pragma unroll
        for (int c = 0; c < 4; c++)
            qf[nt][c] = *(const bf16x8*)(qp + c * 32 + quad * 8);
    }

    f32x4 accO[2][8];
#pragma unroll
    for (int i = 0; i < 2; i++)
#pragma unroll
        for (int j = 0; j < 8; j++) accO[i][j] = (f32x4)0.f;
    float m_s[2] = {-1e30f, -1e30f}, l_s[2] = {0.f, 0.f};
    const float scale2 = 0.08838834764831845f * 1.44269504088896340f; // /sqrt(128)*log2e

    // staging maps
    const int krow4 = t >> 4, kch = t & 15;          // K: rows j*16+krow4, 16B chunk kch
    const int vkp   = t & 63, vdg = (t >> 6) * 32;   // V: keys 2vkp,2vkp+1, dims vdg..+31

    uint4 kst[8], va[4], vb[4];
    float bst = 0.f;
    auto stage_load = [&](int kt) {
        const int k0 = kt * 128;
#pragma unroll
        for (int j = 0; j < 8; j++) {
            int row = j * 16 + krow4;
            kst[j] = *(const uint4_a*)(KV + (size_t)(k0 + row) * KVL + kcol + kch * 8);
        }
        const ushort_t* vp = KV + (size_t)(k0 + 2 * vkp) * KVL + vcol + vdg;
#pragma unroll
        for (int j = 0; j < 4; j++) {
            va[j] = *(const uint4_a*)(vp + j * 8);
            vb[j] = *(const uint4_a*)(vp + KVL + j * 8);
        }
        if (t < 128) bst = amask[k0 + t] ? 0.f : -1e30f;
    };

    const int nkt = (q0 >> 7) + 1;   // 128-key tiles: keys 0 .. q0+127
    stage_load(0);

    for (int kt = 0; kt < nkt; kt++) {
        const int k0 = kt * 128;
        __syncthreads();   // prev tile fully consumed
        // ---- K writes (swizzled b128) ----
#pragma unroll
        for (int j = 0; j < 8; j++) {
            int row = j * 16 + krow4;
            int pc  = kch ^ (row & 7);
            *(uint4_a*)&ks[row * 128 + pc * 8] = kst[j];
        }
        // ---- V transpose writes (2-key b32 packs, swizzled) ----
        {
            unsigned ua[16] = {va[0].x, va[0].y, va[0].z, va[0].w,
                               va[1].x, va[1].y, va[1].z, va[1].w,
                               va[2].x, va[2].y, va[2].z, va[2].w,
                               va[3].x, va[3].y, va[3].z, va[3].w};
            unsigned ub[16] = {vb[0].x, vb[0].y, vb[0].z, vb[0].w,
                               vb[1].x, vb[1].y, vb[1].z, vb[1].w,
                               vb[2].x, vb[2].y, vb[2].z, vb[2].w,
                               vb[3].x, vb[3].y, vb[3].z, vb[3].w};
            const int coff = 2 * (vkp & 3), cch = vkp >> 2;
#pragma unroll
            for (int j = 0; j < 16; j++) {
                int d0 = vdg + 2 * j, d1 = d0 + 1;
                *(uint_a*)&vt[d0 * 128 + (cch ^ (d0 & 7)) * 8 + coff] =
                    (ua[j] & 0xFFFFu) | (ub[j] << 16);
                *(uint_a*)&vt[d1 * 128 + (cch ^ (d1 & 7)) * 8 + coff] =
                    (ua[j] >> 16) | (ub[j] & 0xFFFF0000u);
            }
        }
        if (t < 128) bias[t] = bst;
        __syncthreads();
        if (kt + 1 < nkt) stage_load(kt + 1);   // full compute window in flight

#pragma unroll
        for (int sub = 0; sub < 2; sub++) {
            const int kb = k0 + sub * 64;
            // ---- S^T = K Q^T (A-frag shared across both q-subtiles) ----
            f32x4 s[4][2];
#pragma unroll
            for (int mt = 0; mt < 4; mt++)
#pragma unroll
                for (int nt = 0; nt < 2; nt++) s[mt][nt] = (f32x4)0.f;
#pragma unroll
            for (int c = 0; c < 4; c++)
#pragma unroll
                for (int mt = 0; mt < 4; mt++) {
                    int row = sub * 64 + mt * 16 + l15;
                    int pc  = (4 * c + quad) ^ (l15 & 7);
                    bf16x8 kf = *(const bf16x8*)&ks[row * 128 + pc * 8];
#pragma unroll
                    for (int nt = 0; nt < 2; nt++)
                        s[mt][nt] = __builtin_amdgcn_mfma_f32_16x16x32_bf16(
                            kf, qf[nt][c], s[mt][nt], 0, 0, 0);
                }

            float br[4][4];
#pragma unroll
            for (int mt = 0; mt < 4; mt++) {
                float4 b4 = *(const float4_a*)&bias[sub * 64 + mt * 16 + quad * 4];
                br[mt][0] = b4.x; br[mt][1] = b4.y; br[mt][2] = b4.z; br[mt][3] = b4.w;
            }

            float alpha[2];
            unsigned wlo[2][4], whi[2][4];
#pragma unroll
            for (int nt = 0; nt < 2; nt++) {
                const int qg = q0w + nt * 16 + l15;
                const bool full = (kb + 63 <= q0w + nt * 16);
                float vals[4][4];
                float mx = -1e30f;
#pragma unroll
                for (int mt = 0; mt < 4; mt++)
#pragma unroll
                    for (int r = 0; r < 4; r++) {
                        float v = fmaf(s[mt][nt][r], scale2, br[mt][r]);
                        if (!full) {
                            int kg = kb + mt * 16 + quad * 4 + r;
                            v = (kg > qg) ? -1e30f : v;
                        }
                        vals[mt][r] = v;
                        mx = fmaxf(mx, v);
                    }
                mx = fmaxf(mx, __shfl_xor(mx, 16));
                mx = fmaxf(mx, __shfl_xor(mx, 32));
                float mnew = fmaxf(m_s[nt], mx);
                alpha[nt] = exp2f(m_s[nt] - mnew);
                m_s[nt] = mnew;
                float sum = 0.f;
#pragma unroll
                for (int mt = 0; mt < 4; mt++) {
                    float p0 = exp2f(vals[mt][0] - mnew);
                    float p1 = exp2f(vals[mt][1] - mnew);
                    float p2 = exp2f(vals[mt][2] - mnew);
                    float p3 = exp2f(vals[mt][3] - mnew);
                    sum += (p0 + p1) + (p2 + p3);
                    wlo[nt][mt] = pack2(p0, p1);
                    whi[nt][mt] = pack2(p2, p3);
                }
                sum += __shfl_xor(sum, 16);
                sum += __shfl_xor(sum, 32);
                l_s[nt] = l_s[nt] * alpha[nt] + sum;
            }

            // ---- rescale accO ----
#pragma unroll
            for (int nt = 0; nt < 2; nt++) {
                float a0 = __shfl(alpha[nt], quad * 4 + 0);
                float a1 = __shfl(alpha[nt], quad * 4 + 1);
                float a2 = __shfl(alpha[nt], quad * 4 + 2);
                float a3 = __shfl(alpha[nt], quad * 4 + 3);
#pragma unroll
                for (int j = 0; j < 8; j++) {
                    f32x4 a = accO[nt][j];
                    a[0] *= a0; a[1] *= a1; a[2] *= a2; a[3] *= a3;
                    accO[nt][j] = a;
                }
            }

            // ---- P C->A transpose via ds_bpermute; O += P V ----
#pragma unroll
            for (int kc = 0; kc < 2; kc++) {
                union { unsigned u[4]; bf16x8 v; } pf[2];
#pragma unroll
                for (int nt = 0; nt < 2; nt++)
#pragma unroll
                    for (int t4 = 0; t4 < 4; t4++) {
                        int bpi = ((2 * (quad & 1) + (t4 >> 1)) * 16 + l15) * 4;
                        unsigned slo = (t4 & 1) ? whi[nt][2 * kc]     : wlo[nt][2 * kc];
                        unsigned shi = (t4 & 1) ? whi[nt][2 * kc + 1] : wlo[nt][2 * kc + 1];
                        int ra = __builtin_amdgcn_ds_bpermute(bpi, (int)slo);
                        int rb = __builtin_amdgcn_ds_bpermute(bpi, (int)shi);
                        pf[nt].u[t4] = (unsigned)((quad >> 1) ? rb : ra);
                    }
#pragma unroll
                for (int n8 = 0; n8 < 8; n8++) {
                    int row = n8 * 16 + l15;
                    int pc  = (sub * 8 + 4 * kc + quad) ^ (l15 & 7);
                    bf16x8 vf = *(const bf16x8*)&vt[row * 128 + pc * 8];
#pragma unroll
                    for (int nt = 0; nt < 2; nt++)
                        accO[nt][n8] = __builtin_amdgcn_mfma_f32_16x16x32_bf16(
                            pf[nt].v, vf, accO[nt][n8], 0, 0, 0);
                }
            }
        }
    }

    // ---- epilogue: normalize, store bf16 in-place over Q region ----
#pragma unroll
    for (int nt = 0; nt < 2; nt++) {
        float linv = 1.0f / l_s[nt];
#pragma unroll
        for (int r = 0; r < 4; r++) {
            float lr = __shfl(linv, quad * 4 + r);
            int row = q0w + nt * 16 + quad * 4 + r;
            ushort_t* op = O + (size_t)row * QD + h * HDIM;
#pragma unroll
            for (int n8 = 0; n8 < 8; n8++)
                op[n8 * 16 + l15] = f2bf(accO[nt][n8][r] * lr);
        }
    }
}

// ---------------------------------------------------------------------------
// Memory plan: ws = qbuf/att 16MB | kvbuf (k|v interleaved) 8MB | (woT 8MB
// overwrites kvbuf after flash). d_out scratch until O-GEMM: wqkvT 12MB | xb 16MB.
// ---------------------------------------------------------------------------
extern "C" void kernel_launch(void* const* d_in, const int* in_sizes, int n_in,
                              void* d_out, int out_size, void* d_ws, size_t ws_size,
                              hipStream_t stream)
{
    const float* x     = (const float*)d_in[0];
    const int*   amask = (const int*)d_in[1];
    const int*   pos   = (const int*)d_in[2];
    const float* wq    = (const float*)d_in[3];
    const float* wk    = (const float*)d_in[4];
    const float* wv    = (const float*)d_in[5];
    const float* wo    = (const float*)d_in[6];
    float* out = (float*)d_out;

    ushort_t* wqkvT = (ushort_t*)d_out;                    // [3072][2048] bf16
    ushort_t* xb    = wqkvT + (size_t)3072 * HID;          // [4096][2048] bf16

    ushort_t* qbuf  = (ushort_t*)d_ws;                     // [4096][2048]
    ushort_t* kvbuf = qbuf + (size_t)SEQ * QD;             // [4096][1024] k|v
    ushort_t* woT   = kvbuf;                               // [2048][2048] after flash

    cast_f32_bf16<<<SEQ * HID / 8 / 256, 256, 0, stream>>>(x, xb, SEQ * HID);
    transpose_cast<<<dim3(HID / 32, QD / 32),  256, 0, stream>>>(wq, wqkvT, HID, QD);
    transpose_cast<<<dim3(HID / 32, KVD / 32), 256, 0, stream>>>(wk, wqkvT + (size_t)QD * HID, HID, KVD);
    transpose_cast<<<dim3(HID / 32, KVD / 32), 256, 0, stream>>>(wv, wqkvT + (size_t)(QD + KVD) * HID, HID, KVD);

    // fused QKV projection: cols [0,2048) -> qbuf, [2048,3072) -> kvbuf
    gemm_mfma<<<dim3(3072 / 128, SEQ / 128), 256, 0, stream>>>(
        xb, HID, wqkvT, HID, qbuf, QD, kvbuf, KVL, QD, 3072, HID, 0);

    rope_bf16<<<SEQ * NHEADS * 64 / 256, 256, 0, stream>>>(qbuf, QD, NHEADS, pos);
    rope_bf16<<<SEQ * NKVH  * 64 / 256, 256, 0, stream>>>(kvbuf, KVL, NKVH, pos);

    flash_mfma<<<dim3(NHEADS, SEQ / 128), 256, 0, stream>>>(qbuf, kvbuf, amask, qbuf);

    transpose_cast<<<dim3(QD / 32, HID / 32), 256, 0, stream>>>(wo, woT, QD, HID);
    gemm_mfma<<<dim3(HID / 128, SEQ / 128), 256, 0, stream>>>(
        qbuf, QD, woT, QD, out, HID, out, HID, HID, HID, QD, 1);
}